// Round 1
// baseline (9671.181 us; speedup 1.0000x reference)
//
#include <hip/hip_runtime.h>
#include <stdint.h>

// SkipGRU: T=384, B=48, C=H=256, L=2.
// Plan: GEMM(gi = x@W_ih^T + b_ih) -> single-WG recurrence -> GEMM -> recurrence.
// Recurrence: ONE 1024-thread WG per batch element; the WG holds ALL of W_hh
// (768 KB) in registers (48 float4/lane @ 1024 lanes) and computes r/z/n rows
// for all 256 h-columns. All per-step communication is via LDS + __syncthreads
// -- the previous version split each batch across 2 WGs and paid a ~7.5k-cycle
// device-scope atomic handshake (release/acquire flag + 256 agent-scope ops)
// per timestep; that handshake was ~90% of rec_layer time (VALUBusy was 11%).

#define T_STEPS 384
#define BATCH   48
#define HID     256

__device__ __forceinline__ float sigm_(float x) { return 1.f / (1.f + __expf(-x)); }
__device__ __forceinline__ float tanh_(float x) {
    float ax = fabsf(x);
    float e  = __expf(-2.f * ax);
    float r  = (1.f - e) / (1.f + e);
    return copysignf(r, x);
}

// ---------------------------------------------------------------------------
// GEMM: O[m][n] = sum_k X[m][k] * W[n][k] + B[n];  M=18432, N=768, K=256.
// grid (12, 144), block 256. Tile 128(M) x 64(N), K-chunks of 32 staged in LDS.
// (unchanged from previous round)
// ---------------------------------------------------------------------------
__global__ __launch_bounds__(256, 2) void gemm_nt(const float* __restrict__ X,
                                                  const float* __restrict__ W,
                                                  const float* __restrict__ B,
                                                  float* __restrict__ O)
{
    __shared__ float As[32 * 140];  // [k][m], stride 140 (16B-aligned rows, de-conflicted)
    __shared__ float Bs[32 * 68];   // [k][n], stride 68

    const int tid = threadIdx.x;
    const int tx  = tid & 15;   // n quad
    const int ty  = tid >> 4;   // m octet
    const int n0  = blockIdx.x * 64;
    const int m0  = blockIdx.y * 128;

    float acc[8][4];
#pragma unroll
    for (int i = 0; i < 8; ++i)
#pragma unroll
        for (int j = 0; j < 4; ++j) acc[i][j] = 0.f;

    const float4 bias4 = *reinterpret_cast<const float4*>(B + n0 + tx * 4);

    for (int kc = 0; kc < 8; ++kc) {
        const int k0 = kc * 32;
        float4 a[4], bb[2];
#pragma unroll
        for (int j = 0; j < 4; ++j) {
            int f = tid + 256 * j, r = f >> 3, cq = f & 7;
            a[j] = *reinterpret_cast<const float4*>(X + (size_t)(m0 + r) * 256 + k0 + cq * 4);
        }
#pragma unroll
        for (int j = 0; j < 2; ++j) {
            int f = tid + 256 * j, r = f >> 3, cq = f & 7;
            bb[j] = *reinterpret_cast<const float4*>(W + (size_t)(n0 + r) * 256 + k0 + cq * 4);
        }
        __syncthreads();  // previous chunk's compute done before LDS overwrite
#pragma unroll
        for (int j = 0; j < 4; ++j) {
            int f = tid + 256 * j, r = f >> 3, cq = f & 7;
            As[(cq * 4 + 0) * 140 + r] = a[j].x;
            As[(cq * 4 + 1) * 140 + r] = a[j].y;
            As[(cq * 4 + 2) * 140 + r] = a[j].z;
            As[(cq * 4 + 3) * 140 + r] = a[j].w;
        }
#pragma unroll
        for (int j = 0; j < 2; ++j) {
            int f = tid + 256 * j, r = f >> 3, cq = f & 7;
            Bs[(cq * 4 + 0) * 68 + r] = bb[j].x;
            Bs[(cq * 4 + 1) * 68 + r] = bb[j].y;
            Bs[(cq * 4 + 2) * 68 + r] = bb[j].z;
            Bs[(cq * 4 + 3) * 68 + r] = bb[j].w;
        }
        __syncthreads();
#pragma unroll 8
        for (int kk = 0; kk < 32; ++kk) {
            float4 av0 = *reinterpret_cast<const float4*>(As + kk * 140 + ty * 8);
            float4 av1 = *reinterpret_cast<const float4*>(As + kk * 140 + ty * 8 + 4);
            float4 bv  = *reinterpret_cast<const float4*>(Bs + kk * 68 + tx * 4);
            float am[8] = {av0.x, av0.y, av0.z, av0.w, av1.x, av1.y, av1.z, av1.w};
            float bn[4] = {bv.x, bv.y, bv.z, bv.w};
#pragma unroll
            for (int i = 0; i < 8; ++i)
#pragma unroll
                for (int j = 0; j < 4; ++j) acc[i][j] = fmaf(am[i], bn[j], acc[i][j]);
        }
    }
#pragma unroll
    for (int i = 0; i < 8; ++i) {
        int row = m0 + ty * 8 + i;
        float4 o;
        o.x = acc[i][0] + bias4.x;
        o.y = acc[i][1] + bias4.y;
        o.z = acc[i][2] + bias4.z;
        o.w = acc[i][3] + bias4.w;
        *reinterpret_cast<float4*>(O + (size_t)row * 768 + n0 + tx * 4) = o;
    }
}

// ---------------------------------------------------------------------------
// Recurrence for one layer. grid = 48 (b = blockIdx.x), block 1024 (16 waves).
// Wave w (0..15), group g = lane&15 -> column c = w*16 + g  (covers 0..255).
// Sub s = lane>>4 -> k-slice [s*64, s*64+64); 3 rows x 16 float4 = 192 VGPRs of W.
// hbuf: 4 shifted copies of h (stride 264) -> conflict-free b128 reads
// (slice s read from copy s at word offset s*328: banks {4i,8+4i,16+4i,24+4i}
// across the 4 s-groups are disjoint; within a group all 16 lanes broadcast).
// Per step: matvec -> barrier A -> h/pd updates in LDS -> barrier B -> scalar
// tail. No device-scope traffic at all.
// ---------------------------------------------------------------------------
__global__ __launch_bounds__(1024, 4) void rec_layer(
    const float* __restrict__ GI, float* __restrict__ Yout,
    const float* __restrict__ whh, const float* __restrict__ bhh,
    const float* __restrict__ lwl, const float* __restrict__ lbl,
    const float* __restrict__ hid,
    float* __restrict__ hsout, float* __restrict__ tuout)
{
    __shared__ float hbuf[1056];  // 4 copies x 264
    __shared__ float pdw[16];

    const int tid  = threadIdx.x;
    const int lane = tid & 63;
    const int w    = tid >> 6;    // 0..15
    const int g    = lane & 15;
    const int s    = lane >> 4;   // 0..3
    const int b    = blockIdx.x;  // 0..47
    const int c    = w * 16 + g;  // 0..255

    // W_hh fragments -> registers (read-only, constant-indexed after full unroll)
    float4 Wr[16], Wz[16], Wn[16];
    {
        const float4* wr4 = reinterpret_cast<const float4*>(whh + (size_t)c * 256 + s * 64);
        const float4* wz4 = reinterpret_cast<const float4*>(whh + (size_t)(256 + c) * 256 + s * 64);
        const float4* wn4 = reinterpret_cast<const float4*>(whh + (size_t)(512 + c) * 256 + s * 64);
#pragma unroll
        for (int i = 0; i < 16; ++i) { Wr[i] = wr4[i]; Wz[i] = wz4[i]; Wn[i] = wn4[i]; }
    }

    const float bhr = bhh[c], bhz = bhh[256 + c], bhn = bhh[512 + c];
    const float lwc = lwl[c];
    const float lbv = lbl[0];

    if (tid < 256) {
        float v = hid[tid];
        hbuf[tid] = v; hbuf[264 + tid] = v; hbuf[528 + tid] = v; hbuf[792 + tid] = v;
    }
    __syncthreads();

    float u = 1.f, d = 0.f;
    bool  skip = false;

    for (int t = 0; t < T_STEPS; ++t) {
        const float bu  = rintf(u);        // jnp.round == RNE
        const float obu = 1.f - bu;
        const size_t yrow = ((size_t)t * 48 + b) * 256;

        if (skip) {
            // new_h = h*(1-bu); new_u = clip(u+d,0,1)*(1-bu); d unchanged.
            if (s == 0) {
                float hcv = hbuf[c];
                float nh  = hcv * obu;
                if (bu != 0.f) { hbuf[c] = nh; hbuf[264 + c] = nh; hbuf[528 + c] = nh; hbuf[792 + c] = nh; }
                Yout[yrow + c] = nh;
                if (t == T_STEPS - 1) hsout[b * 256 + c] = nh;
            }
            if (tid == 0) tuout[b * 768 + t] = bu;
            u    = fminf(fmaxf(u + d, 0.f), 1.f) * obu;
            skip = (u < 0.5f);
            __syncthreads();
        } else {
            const size_t gbase = ((size_t)t * 48 + b) * 768 + c;
            const float gir = GI[gbase], giz = GI[gbase + 256], gin = GI[gbase + 512];

            float ar = 0.f, az = 0.f, an = 0.f;
            const float4* h4 = reinterpret_cast<const float4*>(hbuf + s * 328);  // s*264 + s*64
#pragma unroll
            for (int i = 0; i < 16; ++i) {
                float4 hv = h4[i];
                ar = fmaf(Wr[i].x, hv.x, ar); ar = fmaf(Wr[i].y, hv.y, ar);
                ar = fmaf(Wr[i].z, hv.z, ar); ar = fmaf(Wr[i].w, hv.w, ar);
                az = fmaf(Wz[i].x, hv.x, az); az = fmaf(Wz[i].y, hv.y, az);
                az = fmaf(Wz[i].z, hv.z, az); az = fmaf(Wz[i].w, hv.w, az);
                an = fmaf(Wn[i].x, hv.x, an); an = fmaf(Wn[i].y, hv.y, an);
                an = fmaf(Wn[i].z, hv.z, an); an = fmaf(Wn[i].w, hv.w, an);
            }
            ar += __shfl_xor(ar, 16); ar += __shfl_xor(ar, 32);
            az += __shfl_xor(az, 16); az += __shfl_xor(az, 32);
            an += __shfl_xor(an, 16); an += __shfl_xor(an, 32);

            float hcv = hbuf[s * 264 + c];  // old h[c]
            float rr  = sigm_(gir + ar + bhr);
            float zz  = sigm_(giz + az + bhz);
            float nn  = tanh_(gin + rr * (an + bhn));
            float nh  = ((1.f - zz) * nn + zz * hcv) * bu;  // h_ns == new_h (not skipping)
            float pdv = nh * lwc;

            __syncthreads();  // A: all matvec reads of hbuf done before updates
            if (s == 0) {
                hbuf[c] = nh; hbuf[264 + c] = nh; hbuf[528 + c] = nh; hbuf[792 + c] = nh;
                Yout[yrow + c] = nh;
                if (t == T_STEPS - 1) hsout[b * 256 + c] = nh;
            }
            // exact wave butterfly: 4 identical copies per column -> 4*S16, *0.25 exact
            pdv += __shfl_xor(pdv, 1);  pdv += __shfl_xor(pdv, 2);  pdv += __shfl_xor(pdv, 4);
            pdv += __shfl_xor(pdv, 8);  pdv += __shfl_xor(pdv, 16); pdv += __shfl_xor(pdv, 32);
            pdv *= 0.25f;
            if (lane == 0) pdw[w] = pdv;
            if (tid == 0) tuout[b * 768 + t] = bu;
            __syncthreads();  // B: pdw + new h visible to everyone

            float tot = ((pdw[0] + pdw[1]) + (pdw[2] + pdw[3])) + ((pdw[4] + pdw[5]) + (pdw[6] + pdw[7]))
                      + ((pdw[8] + pdw[9]) + (pdw[10] + pdw[11])) + ((pdw[12] + pdw[13]) + (pdw[14] + pdw[15]));
            float dns = sigm_(tot + lbv);  // identical order in every thread -> uniform
            u = dns * bu; d = dns;
            skip = (u < 0.5f);
            // no extra barrier needed: next step's pdw/hbuf writes are after its own barrier A
        }
    }
}

// ---------------------------------------------------------------------------
extern "C" void kernel_launch(void* const* d_in, const int* in_sizes, int n_in,
                              void* d_out, int out_size, void* d_ws, size_t ws_size,
                              hipStream_t stream)
{
    const float* x   = (const float*)d_in[0];  // (384,48,256)
    const float* hid = (const float*)d_in[1];  // (2,1,256)
    const float* wih = (const float*)d_in[2];  // (2,768,256)
    const float* whh = (const float*)d_in[3];  // (2,768,256)
    const float* bih = (const float*)d_in[4];  // (2,768)
    const float* bhh = (const float*)d_in[5];  // (2,768)
    const float* lw  = (const float*)d_in[6];  // (2,1,256)
    const float* lb  = (const float*)d_in[7];  // (2,1)
    float* out = (float*)d_out;

    float* ws = (float*)d_ws;
    float* GI = ws;                         // 18432*768
    float* Y0 = GI + (size_t)18432 * 768;   // 18432*256

    float* OUTy = out;                      // (384,48,256)
    float* HS   = out + (size_t)18432 * 256;// (2,48,256)
    float* TU   = HS + 2 * 48 * 256;        // (48, 768)

    dim3 ggrid(12, 144), gblk(256);
    gemm_nt<<<ggrid, gblk, 0, stream>>>(x, wih, bih, GI);
    rec_layer<<<48, 1024, 0, stream>>>(GI, Y0, whh, bhh, lw, lb, hid, HS, TU);
    gemm_nt<<<ggrid, gblk, 0, stream>>>(Y0, wih + 196608, bih + 768, GI);
    rec_layer<<<48, 1024, 0, stream>>>(GI, OUTy, whh + 196608, bhh + 768, lw + 256, lb + 1,
                                       hid + 256, HS + 12288, TU + 384);
}

// Round 2
// 2203.682 us; speedup vs baseline: 4.3886x; 4.3886x over previous
//
#include <hip/hip_runtime.h>
#include <stdint.h>

// SkipGRU: T=384, B=48, C=H=256, L=2.
// Plan: GEMM(gi = x@W_ih^T + b_ih) -> pairwise-WG recurrence -> GEMM -> recurrence.
//
// Recurrence: 2 WGs per batch element (REQUIRED: one CU's register file is
// 512 regs/lane/SIMD * 4 SIMDs * 64 lanes * 4B = 512 KB < 768 KB = W_hh, so a
// single-WG-per-batch variant spills W to scratch -- measured 3.4x slower).
// Each WG holds half of W_hh (384 KB) in registers (48 float4/lane @ 512 thr).
//
// Cross-WG exchange (the r0 bottleneck, ~90% of step time): replaced the
// {store + release-fence + flag + acquire-poll + separate data loads} protocol
// (~4-5 dependent LLC hops @ ~600-900 cyc each; agent scope is serviced at the
// device coherence point since per-XCD L2s are non-coherent) with
// SELF-SYNCHRONIZING 8B words: each published value is packed as
// (step_tag<<32)|float_bits and the reader polls the exact word it needs until
// tag >= want. Value+readiness arrive in one load -> ~2 dependent hops, no
// fences. Slots are double-buffered by step parity; monotonic tags + the
// publish/consume dependence chain make overwrite-before-consume impossible.
// hbuf/pdw double-buffered in LDS -> 2 barriers/step instead of 4.

#define T_STEPS 384
#define BATCH   48
#define HID     256

__device__ __forceinline__ float sigm_(float x) { return 1.f / (1.f + __expf(-x)); }
__device__ __forceinline__ float tanh_(float x) {
    float ax = fabsf(x);
    float e  = __expf(-2.f * ax);
    float r  = (1.f - e) / (1.f + e);
    return copysignf(r, x);
}

// ---------------------------------------------------------------------------
// GEMM: O[m][n] = sum_k X[m][k] * W[n][k] + B[n];  M=18432, N=768, K=256.
// grid (12, 144), block 256. Tile 128(M) x 64(N), K-chunks of 32 staged in LDS.
// (unchanged; ~150 us each, not the current bottleneck)
// ---------------------------------------------------------------------------
__global__ __launch_bounds__(256, 2) void gemm_nt(const float* __restrict__ X,
                                                  const float* __restrict__ W,
                                                  const float* __restrict__ B,
                                                  float* __restrict__ O)
{
    __shared__ float As[32 * 140];  // [k][m], stride 140 (16B-aligned rows, de-conflicted)
    __shared__ float Bs[32 * 68];   // [k][n], stride 68

    const int tid = threadIdx.x;
    const int tx  = tid & 15;   // n quad
    const int ty  = tid >> 4;   // m octet
    const int n0  = blockIdx.x * 64;
    const int m0  = blockIdx.y * 128;

    float acc[8][4];
#pragma unroll
    for (int i = 0; i < 8; ++i)
#pragma unroll
        for (int j = 0; j < 4; ++j) acc[i][j] = 0.f;

    const float4 bias4 = *reinterpret_cast<const float4*>(B + n0 + tx * 4);

    for (int kc = 0; kc < 8; ++kc) {
        const int k0 = kc * 32;
        float4 a[4], bb[2];
#pragma unroll
        for (int j = 0; j < 4; ++j) {
            int f = tid + 256 * j, r = f >> 3, cq = f & 7;
            a[j] = *reinterpret_cast<const float4*>(X + (size_t)(m0 + r) * 256 + k0 + cq * 4);
        }
#pragma unroll
        for (int j = 0; j < 2; ++j) {
            int f = tid + 256 * j, r = f >> 3, cq = f & 7;
            bb[j] = *reinterpret_cast<const float4*>(W + (size_t)(n0 + r) * 256 + k0 + cq * 4);
        }
        __syncthreads();  // previous chunk's compute done before LDS overwrite
#pragma unroll
        for (int j = 0; j < 4; ++j) {
            int f = tid + 256 * j, r = f >> 3, cq = f & 7;
            As[(cq * 4 + 0) * 140 + r] = a[j].x;
            As[(cq * 4 + 1) * 140 + r] = a[j].y;
            As[(cq * 4 + 2) * 140 + r] = a[j].z;
            As[(cq * 4 + 3) * 140 + r] = a[j].w;
        }
#pragma unroll
        for (int j = 0; j < 2; ++j) {
            int f = tid + 256 * j, r = f >> 3, cq = f & 7;
            Bs[(cq * 4 + 0) * 68 + r] = bb[j].x;
            Bs[(cq * 4 + 1) * 68 + r] = bb[j].y;
            Bs[(cq * 4 + 2) * 68 + r] = bb[j].z;
            Bs[(cq * 4 + 3) * 68 + r] = bb[j].w;
        }
        __syncthreads();
#pragma unroll 8
        for (int kk = 0; kk < 32; ++kk) {
            float4 av0 = *reinterpret_cast<const float4*>(As + kk * 140 + ty * 8);
            float4 av1 = *reinterpret_cast<const float4*>(As + kk * 140 + ty * 8 + 4);
            float4 bv  = *reinterpret_cast<const float4*>(Bs + kk * 68 + tx * 4);
            float am[8] = {av0.x, av0.y, av0.z, av0.w, av1.x, av1.y, av1.z, av1.w};
            float bn[4] = {bv.x, bv.y, bv.z, bv.w};
#pragma unroll
            for (int i = 0; i < 8; ++i)
#pragma unroll
                for (int j = 0; j < 4; ++j) acc[i][j] = fmaf(am[i], bn[j], acc[i][j]);
        }
    }
#pragma unroll
    for (int i = 0; i < 8; ++i) {
        int row = m0 + ty * 8 + i;
        float4 o;
        o.x = acc[i][0] + bias4.x;
        o.y = acc[i][1] + bias4.y;
        o.z = acc[i][2] + bias4.z;
        o.w = acc[i][3] + bias4.w;
        *reinterpret_cast<float4*>(O + (size_t)row * 768 + n0 + tx * 4) = o;
    }
}

// ---------------------------------------------------------------------------
// Recurrence for one layer. grid = 96 (p = blk/48 in {0,1}, b = blk%48), block 512.
// WG p owns h-columns [p*128, p*128+128) and W_hh rows {c, 256+c, 512+c}.
// Wave w (0..7), group g = lane&15 -> column c = p*128 + w*16 + g.
// Sub s = lane>>4 -> k-slice [s*64, s*64+64); 3 rows x 16 float4 = 192 VGPRs of W.
// hbuf: double-buffered (parity hp) x 4 shifted copies of h (stride 264, shift
// 8 words) -> conflict-free b128 reads; non-skip steps write the OTHER parity,
// removing the write-after-read barrier. Skip steps update in place (no comm).
//
// XH: per batch, [2 parity][256] u64 words (tag<<32 | float bits).
// PD: per batch, [2 parity][2 half] u64 words. Tag = ns+1 (count of non-skip
// steps, identical in both WGs since dns = sigm(pd_p + pd_q + lb) is a
// commutative sum -> bit-identical skip trajectory).
// ---------------------------------------------------------------------------
__global__ __launch_bounds__(512, 2) void rec_layer(
    const float* __restrict__ GI, float* __restrict__ Yout,
    const float* __restrict__ whh, const float* __restrict__ bhh,
    const float* __restrict__ lwl, const float* __restrict__ lbl,
    const float* __restrict__ hid,
    unsigned long long* XH, unsigned long long* PD,
    float* __restrict__ hsout, float* __restrict__ tuout)
{
    __shared__ float hbuf[2112];   // 2 parities x (4 copies x 264)
    __shared__ float pdw[2][8];    // double-buffered wave partials

    const int tid  = threadIdx.x;
    const int lane = tid & 63;
    const int w    = tid >> 6;
    const int g    = lane & 15;
    const int s    = lane >> 4;
    const int b    = blockIdx.x % 48;
    const int p    = blockIdx.x / 48;   // pair (i, i+48): likelier same XCD under round-robin
    const int q    = 1 - p;
    const int c    = p * 128 + w * 16 + g;

    // W_hh fragments -> registers (read-only, constant-indexed after full unroll)
    float4 Wr[16], Wz[16], Wn[16];
    {
        const float4* wr4 = reinterpret_cast<const float4*>(whh + (size_t)c * 256 + s * 64);
        const float4* wz4 = reinterpret_cast<const float4*>(whh + (size_t)(256 + c) * 256 + s * 64);
        const float4* wn4 = reinterpret_cast<const float4*>(whh + (size_t)(512 + c) * 256 + s * 64);
#pragma unroll
        for (int i = 0; i < 16; ++i) { Wr[i] = wr4[i]; Wz[i] = wz4[i]; Wn[i] = wn4[i]; }
    }

    const float bhr = bhh[c], bhz = bhh[256 + c], bhn = bhh[512 + c];
    const float lwc = lwl[c];
    const float lbv = lbl[0];

    if (tid < 256) {
        float v = hid[tid];
        hbuf[tid] = v; hbuf[264 + tid] = v; hbuf[528 + tid] = v; hbuf[792 + tid] = v;
    }
    __syncthreads();

    float u = 1.f, d = 0.f;
    bool  skip = false;
    int   ns = 0;   // non-skip step counter; tag = ns+1, slot = ns&1
    int   hp = 0;   // hbuf parity

    unsigned long long* XHb = XH + b * 512;
    unsigned long long* PDb = PD + b * 4;

    for (int t = 0; t < T_STEPS; ++t) {
        const float bu  = rintf(u);        // jnp.round == RNE
        const float obu = 1.f - bu;
        const size_t yrow = ((size_t)t * 48 + b) * 256;

        if (skip) {
            // new_h = h*(1-bu); new_u = clip(u+d,0,1)*(1-bu); d unchanged; no comm.
            float* hb = hbuf + hp * 1056;
            if (s == 0) {
                float hcv = hb[c];
                float nh  = hcv * obu;
                if (bu != 0.f) { hb[c] = nh; hb[264 + c] = nh; hb[528 + c] = nh; hb[792 + c] = nh; }
                Yout[yrow + c] = nh;
                if (t == T_STEPS - 1) hsout[b * 256 + c] = nh;
            }
            if (p == 0 && tid == 0) tuout[b * 768 + t] = bu;
            u    = fminf(fmaxf(u + d, 0.f), 1.f) * obu;
            skip = (u < 0.5f);
            __syncthreads();
        } else {
            const int sl = ns & 1;
            const unsigned int tag = (unsigned int)ns + 1u;
            const size_t gbase = ((size_t)t * 48 + b) * 768 + c;
            const float gir = GI[gbase], giz = GI[gbase + 256], gin = GI[gbase + 512];

            float ar = 0.f, az = 0.f, an = 0.f;
            const float4* h4 = reinterpret_cast<const float4*>(hbuf + hp * 1056 + s * 328);  // s*264 + s*64
#pragma unroll
            for (int i = 0; i < 16; ++i) {
                float4 hv = h4[i];
                ar = fmaf(Wr[i].x, hv.x, ar); ar = fmaf(Wr[i].y, hv.y, ar);
                ar = fmaf(Wr[i].z, hv.z, ar); ar = fmaf(Wr[i].w, hv.w, ar);
                az = fmaf(Wz[i].x, hv.x, az); az = fmaf(Wz[i].y, hv.y, az);
                az = fmaf(Wz[i].z, hv.z, az); az = fmaf(Wz[i].w, hv.w, az);
                an = fmaf(Wn[i].x, hv.x, an); an = fmaf(Wn[i].y, hv.y, an);
                an = fmaf(Wn[i].z, hv.z, an); an = fmaf(Wn[i].w, hv.w, an);
            }
            ar += __shfl_xor(ar, 16); ar += __shfl_xor(ar, 32);
            az += __shfl_xor(az, 16); az += __shfl_xor(az, 32);
            an += __shfl_xor(an, 16); an += __shfl_xor(an, 32);

            float hcv = hbuf[hp * 1056 + s * 264 + c];  // old h[c]
            float rr  = sigm_(gir + ar + bhr);
            float zz  = sigm_(giz + az + bhz);
            float nn  = tanh_(gin + rr * (an + bhn));
            float nh  = ((1.f - zz) * nn + zz * hcv) * bu;  // h_ns == new_h (not skipping)
            float pdv = nh * lwc;

            float* hbn = hbuf + (hp ^ 1) * 1056;   // next-parity buffer (no WAR hazard)
            if (s == 0) {
                hbn[c] = nh; hbn[264 + c] = nh; hbn[528 + c] = nh; hbn[792 + c] = nh;
                Yout[yrow + c] = nh;
                if (t == T_STEPS - 1) hsout[b * 256 + c] = nh;
                unsigned long long pk = ((unsigned long long)tag << 32) |
                                        (unsigned long long)__float_as_uint(nh);
                __hip_atomic_store(XHb + sl * 256 + c, pk, __ATOMIC_RELAXED, __HIP_MEMORY_SCOPE_AGENT);
            }
            // exact wave butterfly: 4 identical copies per column -> 4*S, *0.25 exact
            pdv += __shfl_xor(pdv, 1);  pdv += __shfl_xor(pdv, 2);  pdv += __shfl_xor(pdv, 4);
            pdv += __shfl_xor(pdv, 8);  pdv += __shfl_xor(pdv, 16); pdv += __shfl_xor(pdv, 32);
            pdv *= 0.25f;
            if (lane == 0) pdw[sl][w] = pdv;
            if (p == 0 && tid == 0) tuout[b * 768 + t] = bu;
            __syncthreads();  // B1: pdw + own-half hbn visible WG-wide

            float ownpd = ((pdw[sl][0] + pdw[sl][1]) + (pdw[sl][2] + pdw[sl][3]))
                        + ((pdw[sl][4] + pdw[sl][5]) + (pdw[sl][6] + pdw[sl][7]));
            if (tid == 0) {
                unsigned long long pk = ((unsigned long long)tag << 32) |
                                        (unsigned long long)__float_as_uint(ownpd);
                __hip_atomic_store(PDb + sl * 2 + p, pk, __ATOMIC_RELAXED, __HIP_MEMORY_SCOPE_AGENT);
            }
            if (tid < 128) {
                // self-synchronizing poll of partner's h-half: tag and value in one 8B load
                int qc = q * 128 + tid;
                unsigned long long pk;
                do {
                    pk = __hip_atomic_load(XHb + sl * 256 + qc, __ATOMIC_RELAXED, __HIP_MEMORY_SCOPE_AGENT);
                } while ((unsigned int)(pk >> 32) < tag);
                float v = __uint_as_float((unsigned int)pk);
                hbn[qc] = v; hbn[264 + qc] = v; hbn[528 + qc] = v; hbn[792 + qc] = v;
            }
            unsigned long long pkq;
            do {
                pkq = __hip_atomic_load(PDb + sl * 2 + q, __ATOMIC_RELAXED, __HIP_MEMORY_SCOPE_AGENT);
            } while ((unsigned int)(pkq >> 32) < tag);
            const float pdq = __uint_as_float((unsigned int)pkq);
            __syncthreads();  // B2: partner half of hbn in place before next matvec

            float dns = sigm_((ownpd + pdq) + lbv);  // commutative -> bit-identical in both WGs
            u = dns * bu; d = dns;
            skip = (u < 0.5f);
            ns++; hp ^= 1;
        }
    }
}

// ---------------------------------------------------------------------------
extern "C" void kernel_launch(void* const* d_in, const int* in_sizes, int n_in,
                              void* d_out, int out_size, void* d_ws, size_t ws_size,
                              hipStream_t stream)
{
    const float* x   = (const float*)d_in[0];  // (384,48,256)
    const float* hid = (const float*)d_in[1];  // (2,1,256)
    const float* wih = (const float*)d_in[2];  // (2,768,256)
    const float* whh = (const float*)d_in[3];  // (2,768,256)
    const float* bih = (const float*)d_in[4];  // (2,768)
    const float* bhh = (const float*)d_in[5];  // (2,768)
    const float* lw  = (const float*)d_in[6];  // (2,1,256)
    const float* lb  = (const float*)d_in[7];  // (2,1)
    float* out = (float*)d_out;

    float* ws = (float*)d_ws;
    float* GI = ws;                             // 18432*768 f32
    float* Y0 = GI + (size_t)18432 * 768;       // 18432*256 f32
    unsigned long long* XH0 = (unsigned long long*)(Y0 + (size_t)18432 * 256);
    unsigned long long* XH1 = XH0 + 48 * 512;   // 48 x [2][256] u64 per layer
    unsigned long long* PD0 = XH1 + 48 * 512;   // 48 x [2][2] u64 per layer
    unsigned long long* PD1 = PD0 + 48 * 4;

    float* OUTy = out;                          // (384,48,256)
    float* HS   = out + (size_t)18432 * 256;    // (2,48,256)
    float* TU   = HS + 2 * 48 * 256;            // (48, 768)

    // tags must start at 0 (< first wanted tag 1) regardless of workspace poison
    hipMemsetAsync(XH0, 0, (size_t)(48 * 512 * 2 + 48 * 4 * 2) * sizeof(unsigned long long), stream);

    dim3 ggrid(12, 144), gblk(256);
    gemm_nt<<<ggrid, gblk, 0, stream>>>(x, wih, bih, GI);
    rec_layer<<<96, 512, 0, stream>>>(GI, Y0, whh, bhh, lw, lb, hid, XH0, PD0, HS, TU);
    gemm_nt<<<ggrid, gblk, 0, stream>>>(Y0, wih + 196608, bih + 768, GI);
    rec_layer<<<96, 512, 0, stream>>>(GI, OUTy, whh + 196608, bhh + 768, lw + 256, lb + 1,
                                      hid + 256, XH1, PD1, HS + 12288, TU + 384);
}

// Round 3
// 2032.850 us; speedup vs baseline: 4.7574x; 1.0840x over previous
//
#include <hip/hip_runtime.h>
#include <stdint.h>

// SkipGRU: T=384, B=48, C=H=256, L=2.
// Plan: GEMM(gi = x@W_ih^T + b_ih) -> pairwise-WG recurrence -> GEMM -> recurrence.
//
// Recurrence: 2 WGs per batch element (register-file capacity: W_hh = 768 KB
// > per-CU RF; each WG holds a 384 KB half in registers, 48 float4/lane @ 512
// threads). Cross-WG exchange via self-synchronizing tagged u64 words
// ((tag<<32)|float_bits, poll until tag>=want) -- r2, verified.
//
// r3: software-pipelined matvec. A(t) = W_hh . h(t) is STASHED in registers
// across iterations. Each lane's k-slice is split 32 own-half + 32 partner-half
// k so that, after publishing own h(t+1), the own-half partial of A(t+1) is
// computed WHILE the partner half is in flight (poll load issued before the
// compute, checked after). GI(t+1) is prefetched every iteration (GI streams
// from HBM; its ~900cy latency was serialized per step in r2). Speculation vs
// skip is exact: skip with bu==0 freezes h (stash stays valid); bu==1 zeroes h
// (stash zeroed).

#define T_STEPS 384
#define BATCH   48
#define HID     256

__device__ __forceinline__ float sigm_(float x) { return 1.f / (1.f + __expf(-x)); }
__device__ __forceinline__ float tanh_(float x) {
    float ax = fabsf(x);
    float e  = __expf(-2.f * ax);
    float r  = (1.f - e) / (1.f + e);
    return copysignf(r, x);
}

// ---------------------------------------------------------------------------
// GEMM: O[m][n] = sum_k X[m][k] * W[n][k] + B[n];  M=18432, N=768, K=256.
// grid (12, 144), block 256. Tile 128(M) x 64(N), K-chunks of 32 staged in LDS.
// (unchanged; ~140 us each, not the current bottleneck)
// ---------------------------------------------------------------------------
__global__ __launch_bounds__(256, 2) void gemm_nt(const float* __restrict__ X,
                                                  const float* __restrict__ W,
                                                  const float* __restrict__ B,
                                                  float* __restrict__ O)
{
    __shared__ float As[32 * 140];  // [k][m], stride 140 (16B-aligned rows, de-conflicted)
    __shared__ float Bs[32 * 68];   // [k][n], stride 68

    const int tid = threadIdx.x;
    const int tx  = tid & 15;   // n quad
    const int ty  = tid >> 4;   // m octet
    const int n0  = blockIdx.x * 64;
    const int m0  = blockIdx.y * 128;

    float acc[8][4];
#pragma unroll
    for (int i = 0; i < 8; ++i)
#pragma unroll
        for (int j = 0; j < 4; ++j) acc[i][j] = 0.f;

    const float4 bias4 = *reinterpret_cast<const float4*>(B + n0 + tx * 4);

    for (int kc = 0; kc < 8; ++kc) {
        const int k0 = kc * 32;
        float4 a[4], bb[2];
#pragma unroll
        for (int j = 0; j < 4; ++j) {
            int f = tid + 256 * j, r = f >> 3, cq = f & 7;
            a[j] = *reinterpret_cast<const float4*>(X + (size_t)(m0 + r) * 256 + k0 + cq * 4);
        }
#pragma unroll
        for (int j = 0; j < 2; ++j) {
            int f = tid + 256 * j, r = f >> 3, cq = f & 7;
            bb[j] = *reinterpret_cast<const float4*>(W + (size_t)(n0 + r) * 256 + k0 + cq * 4);
        }
        __syncthreads();  // previous chunk's compute done before LDS overwrite
#pragma unroll
        for (int j = 0; j < 4; ++j) {
            int f = tid + 256 * j, r = f >> 3, cq = f & 7;
            As[(cq * 4 + 0) * 140 + r] = a[j].x;
            As[(cq * 4 + 1) * 140 + r] = a[j].y;
            As[(cq * 4 + 2) * 140 + r] = a[j].z;
            As[(cq * 4 + 3) * 140 + r] = a[j].w;
        }
#pragma unroll
        for (int j = 0; j < 2; ++j) {
            int f = tid + 256 * j, r = f >> 3, cq = f & 7;
            Bs[(cq * 4 + 0) * 68 + r] = bb[j].x;
            Bs[(cq * 4 + 1) * 68 + r] = bb[j].y;
            Bs[(cq * 4 + 2) * 68 + r] = bb[j].z;
            Bs[(cq * 4 + 3) * 68 + r] = bb[j].w;
        }
        __syncthreads();
#pragma unroll 8
        for (int kk = 0; kk < 32; ++kk) {
            float4 av0 = *reinterpret_cast<const float4*>(As + kk * 140 + ty * 8);
            float4 av1 = *reinterpret_cast<const float4*>(As + kk * 140 + ty * 8 + 4);
            float4 bv  = *reinterpret_cast<const float4*>(Bs + kk * 68 + tx * 4);
            float am[8] = {av0.x, av0.y, av0.z, av0.w, av1.x, av1.y, av1.z, av1.w};
            float bn[4] = {bv.x, bv.y, bv.z, bv.w};
#pragma unroll
            for (int i = 0; i < 8; ++i)
#pragma unroll
                for (int j = 0; j < 4; ++j) acc[i][j] = fmaf(am[i], bn[j], acc[i][j]);
        }
    }
#pragma unroll
    for (int i = 0; i < 8; ++i) {
        int row = m0 + ty * 8 + i;
        float4 o;
        o.x = acc[i][0] + bias4.x;
        o.y = acc[i][1] + bias4.y;
        o.z = acc[i][2] + bias4.z;
        o.w = acc[i][3] + bias4.w;
        *reinterpret_cast<float4*>(O + (size_t)row * 768 + n0 + tx * 4) = o;
    }
}

// ---------------------------------------------------------------------------
// Recurrence for one layer. grid = 96 (p = blk/48 in {0,1}, b = blk%48), block 512.
// WG p owns h-columns [p*128, p*128+128) and W_hh rows {c, 256+c, 512+c}.
// Wave w (0..7), group g = lane&15 -> column c = p*128 + w*16 + g.
// Sub s = lane>>4: k-slices [p*128+s*32, +32) (own) and [q*128+s*32, +32)
// (partner); 3 rows x (8+8) float4 = 192 VGPRs of W. Partials folded over s
// via shfl_xor(16/32).
// hbuf: double-buffered (parity hp) x 4 shifted copies of h (stride 264) ->
// conflict-free b128 reads: bank = (8s + 4i) % 32 for both halves.
// XH: per batch, [2 parity][256] u64 (tag<<32 | bits). PD: [2 parity][2 half].
// Tag = ns+1; dns is a commutative 2-term sum -> bit-identical skip trajectory
// in both WGs (verified r2).
// ---------------------------------------------------------------------------
__global__ __launch_bounds__(512, 2) void rec_layer(
    const float* __restrict__ GI, float* __restrict__ Yout,
    const float* __restrict__ whh, const float* __restrict__ bhh,
    const float* __restrict__ lwl, const float* __restrict__ lbl,
    const float* __restrict__ hid,
    unsigned long long* XH, unsigned long long* PD,
    float* __restrict__ hsout, float* __restrict__ tuout)
{
    __shared__ float hbuf[2112];   // 2 parities x (4 copies x 264)
    __shared__ float pdw[2][8];    // double-buffered wave partials

    const int tid  = threadIdx.x;
    const int lane = tid & 63;
    const int w    = tid >> 6;
    const int g    = lane & 15;
    const int s    = lane >> 4;
    const int b    = blockIdx.x % 48;
    const int p    = blockIdx.x / 48;   // pair (i, i+48): likelier same XCD under round-robin
    const int q    = 1 - p;
    const int c    = p * 128 + w * 16 + g;

    // W_hh fragments -> registers. Own-half k and partner-half k sub-slices.
    float4 WrO[8], WzO[8], WnO[8], WrP[8], WzP[8], WnP[8];
    {
        const size_t rR = (size_t)c * 256;
        const size_t rZ = (size_t)(256 + c) * 256;
        const size_t rN = (size_t)(512 + c) * 256;
        const int ko = p * 128 + s * 32;
        const int kq = q * 128 + s * 32;
        const float4* a = reinterpret_cast<const float4*>(whh + rR + ko);
        const float4* bv = reinterpret_cast<const float4*>(whh + rZ + ko);
        const float4* cv = reinterpret_cast<const float4*>(whh + rN + ko);
        const float4* d4 = reinterpret_cast<const float4*>(whh + rR + kq);
        const float4* e4 = reinterpret_cast<const float4*>(whh + rZ + kq);
        const float4* f4 = reinterpret_cast<const float4*>(whh + rN + kq);
#pragma unroll
        for (int i = 0; i < 8; ++i) {
            WrO[i] = a[i];  WzO[i] = bv[i]; WnO[i] = cv[i];
            WrP[i] = d4[i]; WzP[i] = e4[i]; WnP[i] = f4[i];
        }
    }

    const float bhr = bhh[c], bhz = bhh[256 + c], bhn = bhh[512 + c];
    const float lwc = lwl[c];
    const float lbv = lbl[0];

    if (tid < 256) {
        float v = hid[tid];
        hbuf[tid] = v; hbuf[264 + tid] = v; hbuf[528 + tid] = v; hbuf[792 + tid] = v;
    }
    __syncthreads();

    // prologue: gi(0) + stashed A(0) = W_hh . h(0)
    float gir, giz, gin;
    {
        const size_t g0 = (size_t)b * 768 + c;
        gir = GI[g0]; giz = GI[g0 + 256]; gin = GI[g0 + 512];
    }
    float sAr, sAz, sAn;
    {
        float ar = 0.f, az = 0.f, an = 0.f;
        const float4* ho = reinterpret_cast<const float4*>(hbuf + s * 264 + p * 128 + s * 32);
        const float4* hq = reinterpret_cast<const float4*>(hbuf + s * 264 + q * 128 + s * 32);
#pragma unroll
        for (int i = 0; i < 8; ++i) {
            float4 hv = ho[i];
            ar = fmaf(WrO[i].x, hv.x, ar); ar = fmaf(WrO[i].y, hv.y, ar);
            ar = fmaf(WrO[i].z, hv.z, ar); ar = fmaf(WrO[i].w, hv.w, ar);
            az = fmaf(WzO[i].x, hv.x, az); az = fmaf(WzO[i].y, hv.y, az);
            az = fmaf(WzO[i].z, hv.z, az); az = fmaf(WzO[i].w, hv.w, az);
            an = fmaf(WnO[i].x, hv.x, an); an = fmaf(WnO[i].y, hv.y, an);
            an = fmaf(WnO[i].z, hv.z, an); an = fmaf(WnO[i].w, hv.w, an);
        }
#pragma unroll
        for (int i = 0; i < 8; ++i) {
            float4 hv = hq[i];
            ar = fmaf(WrP[i].x, hv.x, ar); ar = fmaf(WrP[i].y, hv.y, ar);
            ar = fmaf(WrP[i].z, hv.z, ar); ar = fmaf(WrP[i].w, hv.w, ar);
            az = fmaf(WzP[i].x, hv.x, az); az = fmaf(WzP[i].y, hv.y, az);
            az = fmaf(WzP[i].z, hv.z, az); az = fmaf(WzP[i].w, hv.w, az);
            an = fmaf(WnP[i].x, hv.x, an); an = fmaf(WnP[i].y, hv.y, an);
            an = fmaf(WnP[i].z, hv.z, an); an = fmaf(WnP[i].w, hv.w, an);
        }
        ar += __shfl_xor(ar, 16); ar += __shfl_xor(ar, 32);
        az += __shfl_xor(az, 16); az += __shfl_xor(az, 32);
        an += __shfl_xor(an, 16); an += __shfl_xor(an, 32);
        sAr = ar; sAz = az; sAn = an;
    }

    float u = 1.f, d = 0.f;
    bool  skip = false;
    int   ns = 0;   // non-skip step counter; tag = ns+1, slot = ns&1
    int   hp = 0;   // hbuf parity

    unsigned long long* XHb = XH + b * 512;
    unsigned long long* PDb = PD + b * 4;

    for (int t = 0; t < T_STEPS; ++t) {
        const float bu  = rintf(u);        // jnp.round == RNE
        const float obu = 1.f - bu;
        const size_t yrow = ((size_t)t * 48 + b) * 256;
        const int tp = (t < T_STEPS - 1) ? t + 1 : t;
        const size_t gpb = ((size_t)tp * 48 + b) * 768 + c;

        if (skip) {
            // new_h = h*(1-bu); new_u = clip(u+d,0,1)*(1-bu); d unchanged; no comm.
            float* hb = hbuf + hp * 1056;
            if (s == 0) {
                float hcv = hb[c];
                float nh  = hcv * obu;
                if (bu != 0.f) { hb[c] = nh; hb[264 + c] = nh; hb[528 + c] = nh; hb[792 + c] = nh; }
                Yout[yrow + c] = nh;
                if (t == T_STEPS - 1) hsout[b * 256 + c] = nh;
            }
            if (bu != 0.f) { sAr = 0.f; sAz = 0.f; sAn = 0.f; }  // h zeroed -> A zeroed
            if (p == 0 && tid == 0) tuout[b * 768 + t] = bu;
            float pr = GI[gpb], pz = GI[gpb + 256], pn = GI[gpb + 512];  // gi(t+1) prefetch
            u    = fminf(fmaxf(u + d, 0.f), 1.f) * obu;
            skip = (u < 0.5f);
            __syncthreads();
            gir = pr; giz = pz; gin = pn;
        } else {
            const int sl = ns & 1;
            const unsigned int tag = (unsigned int)ns + 1u;

            // gates from stashed A(t) + prefetched gi(t)
            float hcv = hbuf[hp * 1056 + s * 264 + c];  // old h[c]
            float rr  = sigm_(gir + sAr + bhr);
            float zz  = sigm_(giz + sAz + bhz);
            float tn  = tanh_(gin + rr * (sAn + bhn));
            float nh  = ((1.f - zz) * tn + zz * hcv) * bu;  // h_ns == new_h (not skipping)
            float pdv = nh * lwc;

            float* hbn = hbuf + (hp ^ 1) * 1056;   // next-parity buffer (no WAR hazard)
            if (s == 0) {
                unsigned long long pk0 = ((unsigned long long)tag << 32) |
                                         (unsigned long long)__float_as_uint(nh);
                __hip_atomic_store(XHb + sl * 256 + c, pk0, __ATOMIC_RELAXED, __HIP_MEMORY_SCOPE_AGENT);
                hbn[c] = nh; hbn[264 + c] = nh; hbn[528 + c] = nh; hbn[792 + c] = nh;
                Yout[yrow + c] = nh;
                if (t == T_STEPS - 1) hsout[b * 256 + c] = nh;
            }
            // exact wave butterfly: 4 identical copies per column -> 4*S, *0.25 exact
            pdv += __shfl_xor(pdv, 1);  pdv += __shfl_xor(pdv, 2);  pdv += __shfl_xor(pdv, 4);
            pdv += __shfl_xor(pdv, 8);  pdv += __shfl_xor(pdv, 16); pdv += __shfl_xor(pdv, 32);
            pdv *= 0.25f;
            if (lane == 0) pdw[sl][w] = pdv;
            if (p == 0 && tid == 0) tuout[b * 768 + t] = bu;
            __syncthreads();  // B1: own-half hbn + pdw visible WG-wide

            float ownpd = ((pdw[sl][0] + pdw[sl][1]) + (pdw[sl][2] + pdw[sl][3]))
                        + ((pdw[sl][4] + pdw[sl][5]) + (pdw[sl][6] + pdw[sl][7]));
            if (tid == 0) {
                unsigned long long pk0 = ((unsigned long long)tag << 32) |
                                         (unsigned long long)__float_as_uint(ownpd);
                __hip_atomic_store(PDb + sl * 2 + p, pk0, __ATOMIC_RELAXED, __HIP_MEMORY_SCOPE_AGENT);
            }

            // issue partner poll load + gi(t+1) prefetch BEFORE the own-half
            // compute: their latency hides under the FMAs below.
            unsigned long long pk = 0;
            if (tid < 128)
                pk = __hip_atomic_load(XHb + sl * 256 + q * 128 + tid, __ATOMIC_RELAXED, __HIP_MEMORY_SCOPE_AGENT);
            float pr = GI[gpb], pz = GI[gpb + 256], pn = GI[gpb + 512];

            // own-half partial of A(t+1) (speculative; exact under skip rules)
            float ar = 0.f, az = 0.f, an = 0.f;
            {
                const float4* ho = reinterpret_cast<const float4*>(hbn + s * 264 + p * 128 + s * 32);
#pragma unroll
                for (int i = 0; i < 8; ++i) {
                    float4 hv = ho[i];
                    ar = fmaf(WrO[i].x, hv.x, ar); ar = fmaf(WrO[i].y, hv.y, ar);
                    ar = fmaf(WrO[i].z, hv.z, ar); ar = fmaf(WrO[i].w, hv.w, ar);
                    az = fmaf(WzO[i].x, hv.x, az); az = fmaf(WzO[i].y, hv.y, az);
                    az = fmaf(WzO[i].z, hv.z, az); az = fmaf(WzO[i].w, hv.w, az);
                    an = fmaf(WnO[i].x, hv.x, an); an = fmaf(WnO[i].y, hv.y, an);
                    an = fmaf(WnO[i].z, hv.z, an); an = fmaf(WnO[i].w, hv.w, an);
                }
            }
            if (tid < 128) {
                while ((unsigned int)(pk >> 32) < tag)
                    pk = __hip_atomic_load(XHb + sl * 256 + q * 128 + tid, __ATOMIC_RELAXED, __HIP_MEMORY_SCOPE_AGENT);
                float v = __uint_as_float((unsigned int)pk);
                int qc = q * 128 + tid;
                hbn[qc] = v; hbn[264 + qc] = v; hbn[528 + qc] = v; hbn[792 + qc] = v;
            }
            __syncthreads();  // B2: partner half of hbn in place

            unsigned long long pkq = __hip_atomic_load(PDb + sl * 2 + q, __ATOMIC_RELAXED, __HIP_MEMORY_SCOPE_AGENT);

            // partner-half partial of A(t+1)
            {
                const float4* hq = reinterpret_cast<const float4*>(hbn + s * 264 + q * 128 + s * 32);
#pragma unroll
                for (int i = 0; i < 8; ++i) {
                    float4 hv = hq[i];
                    ar = fmaf(WrP[i].x, hv.x, ar); ar = fmaf(WrP[i].y, hv.y, ar);
                    ar = fmaf(WrP[i].z, hv.z, ar); ar = fmaf(WrP[i].w, hv.w, ar);
                    az = fmaf(WzP[i].x, hv.x, az); az = fmaf(WzP[i].y, hv.y, az);
                    az = fmaf(WzP[i].z, hv.z, az); az = fmaf(WzP[i].w, hv.w, az);
                    an = fmaf(WnP[i].x, hv.x, an); an = fmaf(WnP[i].y, hv.y, an);
                    an = fmaf(WnP[i].z, hv.z, an); an = fmaf(WnP[i].w, hv.w, an);
                }
            }
            ar += __shfl_xor(ar, 16); ar += __shfl_xor(ar, 32);
            az += __shfl_xor(az, 16); az += __shfl_xor(az, 32);
            an += __shfl_xor(an, 16); an += __shfl_xor(an, 32);
            sAr = ar; sAz = az; sAn = an;

            while ((unsigned int)(pkq >> 32) < tag)
                pkq = __hip_atomic_load(PDb + sl * 2 + q, __ATOMIC_RELAXED, __HIP_MEMORY_SCOPE_AGENT);
            const float pdq = __uint_as_float((unsigned int)pkq);

            float dns = sigm_((ownpd + pdq) + lbv);  // commutative -> bit-identical in both WGs
            u = dns * bu; d = dns;
            skip = (u < 0.5f);
            ns++; hp ^= 1;
            gir = pr; giz = pz; gin = pn;
        }
    }
}

// ---------------------------------------------------------------------------
extern "C" void kernel_launch(void* const* d_in, const int* in_sizes, int n_in,
                              void* d_out, int out_size, void* d_ws, size_t ws_size,
                              hipStream_t stream)
{
    const float* x   = (const float*)d_in[0];  // (384,48,256)
    const float* hid = (const float*)d_in[1];  // (2,1,256)
    const float* wih = (const float*)d_in[2];  // (2,768,256)
    const float* whh = (const float*)d_in[3];  // (2,768,256)
    const float* bih = (const float*)d_in[4];  // (2,768)
    const float* bhh = (const float*)d_in[5];  // (2,768)
    const float* lw  = (const float*)d_in[6];  // (2,1,256)
    const float* lb  = (const float*)d_in[7];  // (2,1)
    float* out = (float*)d_out;

    float* ws = (float*)d_ws;
    float* GI = ws;                             // 18432*768 f32
    float* Y0 = GI + (size_t)18432 * 768;       // 18432*256 f32
    unsigned long long* XH0 = (unsigned long long*)(Y0 + (size_t)18432 * 256);
    unsigned long long* XH1 = XH0 + 48 * 512;   // 48 x [2][256] u64 per layer
    unsigned long long* PD0 = XH1 + 48 * 512;   // 48 x [2][2] u64 per layer
    unsigned long long* PD1 = PD0 + 48 * 4;

    float* OUTy = out;                          // (384,48,256)
    float* HS   = out + (size_t)18432 * 256;    // (2,48,256)
    float* TU   = HS + 2 * 48 * 256;            // (48, 768)

    // tags must start at 0 (< first wanted tag 1) regardless of workspace poison
    hipMemsetAsync(XH0, 0, (size_t)(48 * 512 * 2 + 48 * 4 * 2) * sizeof(unsigned long long), stream);

    dim3 ggrid(12, 144), gblk(256);
    gemm_nt<<<ggrid, gblk, 0, stream>>>(x, wih, bih, GI);
    rec_layer<<<96, 512, 0, stream>>>(GI, Y0, whh, bhh, lw, lb, hid, XH0, PD0, HS, TU);
    gemm_nt<<<ggrid, gblk, 0, stream>>>(Y0, wih + 196608, bih + 768, GI);
    rec_layer<<<96, 512, 0, stream>>>(GI, OUTy, whh + 196608, bhh + 768, lw + 256, lb + 1,
                                      hid + 256, XH1, PD1, HS + 12288, TU + 384);
}